// Round 5
// baseline (279.122 us; speedup 1.0000x reference)
//
#include <hip/hip_runtime.h>
#include <math.h>

#define KK 49
#define H 128
#define W 128
#define C 64
#define NB 4
#define EPS 1e-7f
#define PLANE (H * W)

#define TW 32             // tile width (pixels)
#define TH 2              // tile height (pixels)
#define HW2 38            // halo width  = TW + 6
#define HH2 8             // halo height = TH + 6
#define NPOS (HW2 * HH2)  // 304 halo positions
#define NP2 (2 * NPOS)    // 608 float4 slots per buffer (2 ch-halves of a pass)

// 256 threads, tile 32x2, FOUR threads per pixel (k-quartered 7x7 window):
//   w = tid&31 (pixel col), r = (tid>>5)&1 (pixel row), s2 = tid>>6 (k-quarter,
//   wave-uniform). s2 owns k = s2*12 .. s2*12+11 (+k=48 for s2=3) -> 13 accs max.
// All wave LDS reads/writes and global stores are 32-lane-consecutive float4 /
// dword runs — the R2/R4-proven conflict-free + full-cache-line shape.
// __launch_bounds__(256,4): with 256-thr blocks, "4 waves/EU" == "4 blocks/CU"
// under EITHER interpretation -> 16 waves/CU, VGPR cap 128 (R4's (512,4) was
// read as 32 waves/CU -> 64-VGPR cap -> 518 MB scratch spill traffic).
__global__ __launch_bounds__(256, 4) void rsa_kernel(const float* __restrict__ x,
                                                     float* __restrict__ out) {
    __shared__ float4 sx[2][NP2];      // 19.0 KB: [buf][half*NPOS + pos]
    __shared__ float  sn2[NP2];        // 2.4 KB : per-half sum of squares
    __shared__ float  snf[NPOS];       // 1.2 KB : final norms
    __shared__ float  comb[4][TW * TH];// 1.0 KB : softmax cross-quarter combine

    const int tid = threadIdx.x;
    const int w   = tid & 31;
    const int r   = (tid >> 5) & 1;
    const int s2  = tid >> 6;          // wave-uniform (wave i -> s2 = i)
    const int w0  = blockIdx.x * TW;
    const int h0  = blockIdx.y * TH;
    const int b   = blockIdx.z;
    const float* __restrict__ xb = x + (size_t)b * C * PLANE;

    const bool has13 = (s2 == 3);
    const int  kbase = s2 * 12;

    // ---- per-thread window-address table (12-13 LDS float4 indices)
    const int caddr = (r + 3) * HW2 + (w + 3);
    int lofs[13];
#pragma unroll
    for (int l = 0; l < 13; ++l) {
        int k = kbase + l;
        if (l == 12 && !has13) { lofs[l] = caddr; continue; }
        int di = k / 7, dj = k - di * 7;
        lofs[l] = (r + di) * HW2 + (w + dj);
    }

    // ---- staging slot metadata (fixed across passes): slot i = tid + 256*j
    int goff[3], pos[3], hh[3];
    bool act[3], inb[3];
#pragma unroll
    for (int j = 0; j < 3; ++j) {
        int i = tid + j * 256;
        act[j] = (i < NP2);
        int ii = act[j] ? i : 0;
        int h  = (ii >= NPOS) ? 1 : 0;
        int p  = ii - h * NPOS;
        int rr = p / HW2, cc = p - rr * HW2;
        int gh = h0 - 3 + rr, gw = w0 - 3 + cc;
        inb[j]  = (gh >= 0) && (gh < H) && (gw >= 0) && (gw < W);
        goff[j] = gh * W + gw;
        pos[j]  = ii;                  // flat index within one buffer
        hh[j]   = h;                   // channel-half of the pass
    }

    float4 pf[3];
    float  np[3] = {0.f, 0.f, 0.f};

    auto load_pass = [&](int t) {
#pragma unroll
        for (int j = 0; j < 3; ++j) {
            float4 v = make_float4(0.f, 0.f, 0.f, 0.f);
            if (act[j] && inb[j]) {
                const float* p = xb + (size_t)(t * 8 + hh[j] * 4) * PLANE + goff[j];
                v.x = p[0];
                v.y = p[PLANE];
                v.z = p[2 * PLANE];
                v.w = p[3 * PLANE];
            }
            pf[j] = v;
        }
    };

    auto write_pass = [&](int buf) {
#pragma unroll
        for (int j = 0; j < 3; ++j) {
            if (act[j]) {
                sx[buf][pos[j]] = pf[j];
                float4 v = pf[j];
                np[j] += v.x * v.x + v.y * v.y + v.z * v.z + v.w * v.w;
            }
        }
    };

    float acc[13];
#pragma unroll
    for (int l = 0; l < 13; ++l) acc[l] = 0.f;

    auto compute = [&](int buf) {
        const float4* __restrict__ base = sx[buf];
        const float4 c0 = base[caddr];
        const float4 c1 = base[NPOS + caddr];
#pragma unroll
        for (int l = 0; l < 13; ++l) {
            if (l < 12 || has13) {   // wave-uniform predicate
                const float4 n0 = base[lofs[l]];
                const float4 n1 = base[NPOS + lofs[l]];
                acc[l] += c0.x * n0.x; acc[l] += c0.y * n0.y;
                acc[l] += c0.z * n0.z; acc[l] += c0.w * n0.w;
                acc[l] += c1.x * n1.x; acc[l] += c1.y * n1.y;
                acc[l] += c1.z * n1.z; acc[l] += c1.w * n1.w;
            }
        }
    };

    // ---- software-pipelined main loop: prefetch t+1 while computing t
    load_pass(0);
    write_pass(0);
    __syncthreads();
#pragma unroll 2
    for (int t = 0; t < 8; ++t) {
        const int buf = t & 1;
        if (t < 7) load_pass(t + 1);
        compute(buf);
        if (t < 7) write_pass(buf ^ 1);
        __syncthreads();
    }

    // ---- norms: slot owners hold per-half sums over all 8 passes
#pragma unroll
    for (int j = 0; j < 3; ++j)
        if (act[j]) sn2[pos[j]] = np[j];
    __syncthreads();
    for (int i = tid; i < NPOS; i += 256) snf[i] = sqrtf(sn2[i] + sn2[i + NPOS]);
    __syncthreads();

    // ---- cosine sim + cross-quarter softmax
    const float nc = snf[caddr];
    float m = -1e30f;
#pragma unroll
    for (int l = 0; l < 13; ++l) {
        if (l < 12 || has13) {
            const float nn = snf[lofs[l]];
            const float sv = __fdividef(acc[l], nc * nn + EPS);
            acc[l] = sv;
            m = fmaxf(m, sv);
        }
    }
    const int pxi = r * TW + w;
    comb[s2][pxi] = m;
    __syncthreads();
    m = fmaxf(fmaxf(comb[0][pxi], comb[1][pxi]), fmaxf(comb[2][pxi], comb[3][pxi]));
    __syncthreads();

    float sum = 0.f;
#pragma unroll
    for (int l = 0; l < 13; ++l) {
        if (l < 12 || has13) {
            const float e = __expf(acc[l] - m);
            acc[l] = e;
            sum += e;
        }
    }
    comb[s2][pxi] = sum;
    __syncthreads();
    sum = (comb[0][pxi] + comb[1][pxi]) + (comb[2][pxi] + comb[3][pxi]);
    const float inv = __fdividef(1.f, sum);

    float* op = out + (((size_t)b * KK + kbase) << 14) + ((h0 + r) << 7) + (w0 + w);
#pragma unroll
    for (int l = 0; l < 13; ++l) {
        if (l < 12 || has13)
            op[(size_t)l << 14] = acc[l] * inv;
    }
}

extern "C" void kernel_launch(void* const* d_in, const int* in_sizes, int n_in,
                              void* d_out, int out_size, void* d_ws, size_t ws_size,
                              hipStream_t stream) {
    const float* x = (const float*)d_in[0];
    float* out = (float*)d_out;

    dim3 block(256, 1, 1);
    dim3 grid(W / TW, H / TH, NB);  // 4 x 64 x 4 = 1024 blocks (4 per CU, 16 waves/CU)
    rsa_kernel<<<grid, block, 0, stream>>>(x, out);
}

// Round 7
// 99.830 us; speedup vs baseline: 2.7960x; 2.7960x over previous
//
#include <hip/hip_runtime.h>
#include <math.h>

#define KK 49
#define H 128
#define W 128
#define C 64
#define NB 4
#define EPS 1e-7f
#define PLANE (H * W)

#define TW 32             // tile width (pixels)
#define TH 2              // tile height (pixels)
#define HW2 38            // halo width  = TW + 6
#define HH2 8             // halo height = TH + 6
#define NPOS (HW2 * HH2)  // 304 halo positions
#define NP2 (2 * NPOS)    // 608 float4 slots per buffer (2 ch-halves of a pass)

// 256 threads, tile 32x2, FOUR threads per pixel (k-quartered 7x7 window):
//   w = tid&31 (pixel col), r = (tid>>5)&1 (pixel row), s2 = tid>>6 (k-quarter,
//   wave-uniform). s2 owns k = s2*12 .. s2*12+11 (+k=48 for s2=3) -> 13 accs max.
// All wave LDS reads/writes and global stores are 32-lane-consecutive float4 /
// dword runs — R2/R5-proven conflict-free (SQ_LDS_BANK_CONFLICT == 0).
//
// LAUNCH BOUNDS (hard-won): on this toolchain the 2nd arg empirically caps
// VGPRs at 256/arg: arg=1->256 (R2), 2->128 (R3), 4->64 (R4/R5: ~90 live regs
// forced into 64 -> 500+ MB scratch spill traffic, 4x slowdown). arg=2 is the
// max safe value for this kernel (~90 live regs). Occupancy comes from the
// grid (1024 blocks); at <=128 VGPR the HW allows 16 waves/CU on its own.
// R6 submission of this exact source died in the harness (host-side SIGABRT,
// no kernel output) — resubmitted unchanged as an infra-flake check.
__global__ __launch_bounds__(256, 2) void rsa_kernel(const float* __restrict__ x,
                                                     float* __restrict__ out) {
    __shared__ float4 sx[2][NP2];      // 19.0 KB: [buf][half*NPOS + pos]
    __shared__ float  sn2[NP2];        // 2.4 KB : per-half sum of squares
    __shared__ float  snf[NPOS];       // 1.2 KB : final norms
    __shared__ float  comb[4][TW * TH];// 1.0 KB : softmax cross-quarter combine

    const int tid = threadIdx.x;
    const int w   = tid & 31;
    const int r   = (tid >> 5) & 1;
    const int s2  = tid >> 6;          // wave-uniform (wave i -> s2 = i)
    const int w0  = blockIdx.x * TW;
    const int h0  = blockIdx.y * TH;
    const int b   = blockIdx.z;
    const float* __restrict__ xb = x + (size_t)b * C * PLANE;

    const bool has13 = (s2 == 3);
    const int  kbase = s2 * 12;

    // ---- per-thread window-address table (12-13 LDS float4 indices)
    const int caddr = (r + 3) * HW2 + (w + 3);
    int lofs[13];
#pragma unroll
    for (int l = 0; l < 13; ++l) {
        int k = kbase + l;
        if (l == 12 && !has13) { lofs[l] = caddr; continue; }
        int di = k / 7, dj = k - di * 7;
        lofs[l] = (r + di) * HW2 + (w + dj);
    }

    // ---- staging slot metadata (fixed across passes): slot i = tid + 256*j
    int goff[3], pos[3], hh[3];
    bool act[3], inb[3];
#pragma unroll
    for (int j = 0; j < 3; ++j) {
        int i = tid + j * 256;
        act[j] = (i < NP2);
        int ii = act[j] ? i : 0;
        int h  = (ii >= NPOS) ? 1 : 0;
        int p  = ii - h * NPOS;
        int rr = p / HW2, cc = p - rr * HW2;
        int gh = h0 - 3 + rr, gw = w0 - 3 + cc;
        inb[j]  = (gh >= 0) && (gh < H) && (gw >= 0) && (gw < W);
        goff[j] = gh * W + gw;
        pos[j]  = ii;                  // flat index within one buffer
        hh[j]   = h;                   // channel-half of the pass
    }

    float4 pf[3];
    float  np[3] = {0.f, 0.f, 0.f};

    auto load_pass = [&](int t) {
#pragma unroll
        for (int j = 0; j < 3; ++j) {
            float4 v = make_float4(0.f, 0.f, 0.f, 0.f);
            if (act[j] && inb[j]) {
                const float* p = xb + (size_t)(t * 8 + hh[j] * 4) * PLANE + goff[j];
                v.x = p[0];
                v.y = p[PLANE];
                v.z = p[2 * PLANE];
                v.w = p[3 * PLANE];
            }
            pf[j] = v;
        }
    };

    auto write_pass = [&](int buf) {
#pragma unroll
        for (int j = 0; j < 3; ++j) {
            if (act[j]) {
                sx[buf][pos[j]] = pf[j];
                float4 v = pf[j];
                np[j] += v.x * v.x + v.y * v.y + v.z * v.z + v.w * v.w;
            }
        }
    };

    float acc[13];
#pragma unroll
    for (int l = 0; l < 13; ++l) acc[l] = 0.f;

    auto compute = [&](int buf) {
        const float4* __restrict__ base = sx[buf];
        const float4 c0 = base[caddr];
        const float4 c1 = base[NPOS + caddr];
#pragma unroll
        for (int l = 0; l < 13; ++l) {
            if (l < 12 || has13) {   // wave-uniform predicate
                const float4 n0 = base[lofs[l]];
                const float4 n1 = base[NPOS + lofs[l]];
                acc[l] += c0.x * n0.x; acc[l] += c0.y * n0.y;
                acc[l] += c0.z * n0.z; acc[l] += c0.w * n0.w;
                acc[l] += c1.x * n1.x; acc[l] += c1.y * n1.y;
                acc[l] += c1.z * n1.z; acc[l] += c1.w * n1.w;
            }
        }
    };

    // ---- software-pipelined main loop: prefetch t+1 while computing t
    load_pass(0);
    write_pass(0);
    __syncthreads();
#pragma unroll 2
    for (int t = 0; t < 8; ++t) {
        const int buf = t & 1;
        if (t < 7) load_pass(t + 1);
        compute(buf);
        if (t < 7) write_pass(buf ^ 1);
        __syncthreads();
    }

    // ---- norms: slot owners hold per-half sums over all 8 passes
#pragma unroll
    for (int j = 0; j < 3; ++j)
        if (act[j]) sn2[pos[j]] = np[j];
    __syncthreads();
    for (int i = tid; i < NPOS; i += 256) snf[i] = sqrtf(sn2[i] + sn2[i + NPOS]);
    __syncthreads();

    // ---- cosine sim + cross-quarter softmax
    const float nc = snf[caddr];
    float m = -1e30f;
#pragma unroll
    for (int l = 0; l < 13; ++l) {
        if (l < 12 || has13) {
            const float nn = snf[lofs[l]];
            const float sv = __fdividef(acc[l], nc * nn + EPS);
            acc[l] = sv;
            m = fmaxf(m, sv);
        }
    }
    const int pxi = r * TW + w;
    comb[s2][pxi] = m;
    __syncthreads();
    m = fmaxf(fmaxf(comb[0][pxi], comb[1][pxi]), fmaxf(comb[2][pxi], comb[3][pxi]));
    __syncthreads();

    float sum = 0.f;
#pragma unroll
    for (int l = 0; l < 13; ++l) {
        if (l < 12 || has13) {
            const float e = __expf(acc[l] - m);
            acc[l] = e;
            sum += e;
        }
    }
    comb[s2][pxi] = sum;
    __syncthreads();
    sum = (comb[0][pxi] + comb[1][pxi]) + (comb[2][pxi] + comb[3][pxi]);
    const float inv = __fdividef(1.f, sum);

    float* op = out + (((size_t)b * KK + kbase) << 14) + ((h0 + r) << 7) + (w0 + w);
#pragma unroll
    for (int l = 0; l < 13; ++l) {
        if (l < 12 || has13)
            op[(size_t)l << 14] = acc[l] * inv;
    }
}

extern "C" void kernel_launch(void* const* d_in, const int* in_sizes, int n_in,
                              void* d_out, int out_size, void* d_ws, size_t ws_size,
                              hipStream_t stream) {
    const float* x = (const float*)d_in[0];
    float* out = (float*)d_out;

    dim3 block(256, 1, 1);
    dim3 grid(W / TW, H / TH, NB);  // 4 x 64 x 4 = 1024 blocks (4 per CU, 16 waves/CU)
    rsa_kernel<<<grid, block, 0, stream>>>(x, out);
}

// Round 8
// 82.923 us; speedup vs baseline: 3.3660x; 1.2039x over previous
//
#include <hip/hip_runtime.h>
#include <math.h>

#define KK 49
#define H 128
#define W 128
#define C 64
#define NB 4
#define EPS 1e-7f
#define PLANE (H * W)

#define TW 32              // tile width (pixels)
#define TH 2               // tile height (pixels)
#define HW2 38             // halo width  = TW + 6
#define HH2 8              // halo height = TH + 6
#define NPOS (HW2 * HH2)   // 304 halo positions
#define NP2 (2 * NPOS)     // 608 float4 slots per buffer (2 ch-halves of a pass)
#define CADDR (3 * HW2 + 3)// center offset within a thread's window base (117)

// Per-quarter loops with COMPILE-TIME window offsets (s2 is wave-uniform, so we
// branch on it and let ds_read_b128 use immediate offsets; max byte offset
// (NPOS+234)*16 = 8608 fits the 16-bit DS offset field). This removes the
// runtime lofs[13] table that R7's counters showed being spilled to scratch
// (WRITE_SIZE 41 MB vs 12.25 ideal; VALUBusy 2.6x the instruction-count model).

template<int Q>
__device__ __forceinline__ void compute_q(const float4* __restrict__ basep,
                                          float (&acc)[13]) {
    constexpr int NK = (Q == 3) ? 13 : 12;
    const float4 c0 = basep[CADDR];
    const float4 c1 = basep[NPOS + CADDR];
#pragma unroll
    for (int l = 0; l < NK; ++l) {
        const int k = Q * 12 + l;                    // compile-time after unroll
        const int off = (k / 7) * HW2 + (k % 7);
        const float4 n0 = basep[off];
        const float4 n1 = basep[NPOS + off];
        acc[l] += c0.x * n0.x; acc[l] += c0.y * n0.y;
        acc[l] += c0.z * n0.z; acc[l] += c0.w * n0.w;
        acc[l] += c1.x * n1.x; acc[l] += c1.y * n1.y;
        acc[l] += c1.z * n1.z; acc[l] += c1.w * n1.w;
    }
}

template<int Q>
__device__ __forceinline__ void sim_and_max(const float* __restrict__ snb,
                                            float (&acc)[13], float& m) {
    constexpr int NK = (Q == 3) ? 13 : 12;
    const float nc = snb[CADDR];
#pragma unroll
    for (int l = 0; l < NK; ++l) {
        const int k = Q * 12 + l;
        const int off = (k / 7) * HW2 + (k % 7);
        const float nn = snb[off];
        const float sv = __fdividef(acc[l], nc * nn + EPS);
        acc[l] = sv;
        m = fmaxf(m, sv);
    }
}

template<int Q>
__device__ __forceinline__ void exp_and_sum(float (&acc)[13], float m, float& sum) {
    constexpr int NK = (Q == 3) ? 13 : 12;
#pragma unroll
    for (int l = 0; l < NK; ++l) {
        const float e = __expf(acc[l] - m);
        acc[l] = e;
        sum += e;
    }
}

template<int Q>
__device__ __forceinline__ void store_q(float* __restrict__ op,
                                        const float (&acc)[13], float inv) {
    constexpr int NK = (Q == 3) ? 13 : 12;
#pragma unroll
    for (int l = 0; l < NK; ++l)
        op[(size_t)l << 14] = acc[l] * inv;
}

// Dispatch a statement with constexpr Q selected by the wave-uniform s2.
// Branches are wave-uniform and contain NO barriers (barriers stay common).
#define DISPATCH_Q(stmt)                                      \
    do {                                                      \
        if (s2 == 0)      { constexpr int Q = 0; stmt; }      \
        else if (s2 == 1) { constexpr int Q = 1; stmt; }      \
        else if (s2 == 2) { constexpr int Q = 2; stmt; }      \
        else              { constexpr int Q = 3; stmt; }      \
    } while (0)

// 256 threads, tile 32x2, FOUR threads per pixel (k-quartered 7x7 window):
//   w = tid&31, r = (tid>>5)&1, s2 = tid>>6 (wave-uniform k-quarter).
// All wave LDS reads/writes and global stores are 32-lane-consecutive float4 /
// dword runs — R2/R5/R7-proven conflict-free (SQ_LDS_BANK_CONFLICT == 0).
// LAUNCH BOUNDS (hard-won): 2nd arg empirically caps VGPRs at 256/arg
// (R4/R5: arg=4 -> 64-reg cap -> 500+ MB scratch traffic). arg=2 (128) is the
// operating point; occupancy comes from the 1024-block grid (4/CU, 16 waves).
__global__ __launch_bounds__(256, 2) void rsa_kernel(const float* __restrict__ x,
                                                     float* __restrict__ out) {
    __shared__ float4 sx[2][NP2];      // 19.0 KB: [buf][half*NPOS + pos]
    __shared__ float  sn2[NP2];        // 2.4 KB : per-half sum of squares
    __shared__ float  snf[NPOS];       // 1.2 KB : final norms
    __shared__ float  comb[4][TW * TH];// 1.0 KB : softmax cross-quarter combine

    const int tid = threadIdx.x;
    const int w   = tid & 31;
    const int r   = (tid >> 5) & 1;
    const int s2  = tid >> 6;          // wave-uniform (wave i -> s2 = i)
    const int w0  = blockIdx.x * TW;
    const int h0  = blockIdx.y * TH;
    const int b   = blockIdx.z;
    const float* __restrict__ xb = x + (size_t)b * C * PLANE;

    // thread's window-origin bases (all window offsets become immediates)
    const int roww = r * HW2 + w;
    const float4* const base4[2] = { &sx[0][0] + roww, &sx[1][0] + roww };

    // ---- staging slot metadata (fixed across passes): slot i = tid + 256*j
    int goff[3], pos[3], hh[3];
    bool act[3], inb[3];
#pragma unroll
    for (int j = 0; j < 3; ++j) {
        int i = tid + j * 256;
        act[j] = (i < NP2);
        int ii = act[j] ? i : 0;
        int h  = (ii >= NPOS) ? 1 : 0;
        int p  = ii - h * NPOS;
        int rr = p / HW2, cc = p - rr * HW2;
        int gh = h0 - 3 + rr, gw = w0 - 3 + cc;
        inb[j]  = (gh >= 0) && (gh < H) && (gw >= 0) && (gw < W);
        goff[j] = gh * W + gw;
        pos[j]  = ii;                  // flat index within one buffer
        hh[j]   = h;                   // channel-half of the pass
    }

    float4 pf[3];
    float  np[3] = {0.f, 0.f, 0.f};

    auto load_pass = [&](int t) {
#pragma unroll
        for (int j = 0; j < 3; ++j) {
            float4 v = make_float4(0.f, 0.f, 0.f, 0.f);
            if (act[j] && inb[j]) {
                const float* p = xb + (size_t)(t * 8 + hh[j] * 4) * PLANE + goff[j];
                v.x = p[0];
                v.y = p[PLANE];
                v.z = p[2 * PLANE];
                v.w = p[3 * PLANE];
            }
            pf[j] = v;
        }
    };

    auto write_pass = [&](int buf) {
#pragma unroll
        for (int j = 0; j < 3; ++j) {
            if (act[j]) {
                sx[buf][pos[j]] = pf[j];
                float4 v = pf[j];
                np[j] += v.x * v.x + v.y * v.y + v.z * v.z + v.w * v.w;
            }
        }
    };

    float acc[13];
#pragma unroll
    for (int l = 0; l < 13; ++l) acc[l] = 0.f;

    // ---- software-pipelined main loop: prefetch t+1 while computing t
    load_pass(0);
    write_pass(0);
    __syncthreads();
#pragma unroll 2
    for (int t = 0; t < 8; ++t) {
        const int buf = t & 1;
        if (t < 7) load_pass(t + 1);
        DISPATCH_Q(compute_q<Q>(base4[buf], acc));
        if (t < 7) write_pass(buf ^ 1);
        __syncthreads();
    }

    // ---- norms: slot owners hold per-half sums over all 8 passes
#pragma unroll
    for (int j = 0; j < 3; ++j)
        if (act[j]) sn2[pos[j]] = np[j];
    __syncthreads();
    for (int i = tid; i < NPOS; i += 256) snf[i] = sqrtf(sn2[i] + sn2[i + NPOS]);
    __syncthreads();

    // ---- cosine sim + cross-quarter softmax
    const float* snb = &snf[0] + roww;
    float m = -1e30f;
    DISPATCH_Q(sim_and_max<Q>(snb, acc, m));

    const int pxi = r * TW + w;
    comb[s2][pxi] = m;
    __syncthreads();
    m = fmaxf(fmaxf(comb[0][pxi], comb[1][pxi]), fmaxf(comb[2][pxi], comb[3][pxi]));
    __syncthreads();

    float sum = 0.f;
    DISPATCH_Q(exp_and_sum<Q>(acc, m, sum));
    comb[s2][pxi] = sum;
    __syncthreads();
    sum = (comb[0][pxi] + comb[1][pxi]) + (comb[2][pxi] + comb[3][pxi]);
    const float inv = __fdividef(1.f, sum);

    float* op = out + (((size_t)b * KK + s2 * 12) << 14) + ((h0 + r) << 7) + (w0 + w);
    DISPATCH_Q(store_q<Q>(op, acc, inv));
}

extern "C" void kernel_launch(void* const* d_in, const int* in_sizes, int n_in,
                              void* d_out, int out_size, void* d_ws, size_t ws_size,
                              hipStream_t stream) {
    const float* x = (const float*)d_in[0];
    float* out = (float*)d_out;

    dim3 block(256, 1, 1);
    dim3 grid(W / TW, H / TH, NB);  // 4 x 64 x 4 = 1024 blocks (4 per CU, 16 waves/CU)
    rsa_kernel<<<grid, block, 0, stream>>>(x, out);
}

// Round 9
// 81.039 us; speedup vs baseline: 3.4443x; 1.0233x over previous
//
#include <hip/hip_runtime.h>
#include <math.h>

#define KK 49
#define H 128
#define W 128
#define C 64
#define NB 4
#define EPS 1e-7f
#define PLANE (H * W)

#define TW 32              // tile width (pixels)
#define TH 4               // tile height (pixels)
#define HW2 38             // halo width  = TW + 6
#define HH2 10             // halo height = TH + 6
#define NPOS (HW2 * HH2)   // 380 halo positions
#define NP2 (2 * NPOS)     // 760 float4 slots per buffer (2 ch-halves of a pass)

// R9: vertical 2-pixel pairing. 256 threads, tile 32x4:
//   w  = tid&31   pixel col
//   hs = bit5     channel-half (IN-wave -> shfl_xor(32) reduce, no LDS)
//   pr = bit6     pixel-pair: rows {2pr, 2pr+1}          (wave-uniform)
//   kh = bit7     k-half: kh=0 -> k 0..23, kh=1 -> 24..48 (wave-uniform)
// One window read serves BOTH pixels of the pair (windows overlap 6 of 7 rows):
// 31-32 union reads + 2 centers per pass feed ~200 FMAs -> 8.5 wave-reads/px
// (R8: 14). All wave LDS ops are 32-lane-consecutive float4 runs (hs selects
// block A/B per half-wave) — the proven conflict-free shape.
// kh is wave-uniform -> template dispatch keeps every DS offset an immediate
// (R8's fix for the spilled runtime offset table).
// LAUNCH BOUNDS (hard-won): 2nd arg caps VGPRs at 256/arg on this toolchain
// (arg=4 -> 64-reg cap -> 500+MB scratch, R4/R5). arg=2 -> 128 cap; ~95 live.

template<int KH>
__device__ __forceinline__ void compute_q(const float4* __restrict__ bp,
                                          float (&a0)[25], float (&a1)[25]) {
    const float4 c0 = bp[3 * HW2 + 3];   // px0 center
    const float4 c1 = bp[4 * HW2 + 3];   // px1 center
#pragma unroll
    for (int u = (KH ? 3 : 0); u <= (KH ? 7 : 4); ++u) {
#pragma unroll
        for (int dj = 0; dj < 7; ++dj) {
            // validity of union position (u,dj) for px0 (di=u) and px1 (di=u-1)
            const bool v0 = KH ? (u >= 3 && u <= 6 && (u > 3 || dj >= 3))
                               : (u <= 3 && (u < 3 || dj <= 2));
            const bool v1 = KH ? (u >= 4 && (u > 4 || dj >= 3))
                               : (u >= 1 && u <= 4 && (u < 4 || dj <= 2));
            if (v0 || v1) {
                const float4 nv = bp[u * HW2 + dj];
                if (v0) {
                    const int l = KH ? (u * 7 + dj - 24) : (u * 7 + dj);
                    a0[l] += c0.x * nv.x; a0[l] += c0.y * nv.y;
                    a0[l] += c0.z * nv.z; a0[l] += c0.w * nv.w;
                }
                if (v1) {
                    const int l = KH ? ((u - 1) * 7 + dj - 24) : ((u - 1) * 7 + dj);
                    a1[l] += c1.x * nv.x; a1[l] += c1.y * nv.y;
                    a1[l] += c1.z * nv.z; a1[l] += c1.w * nv.w;
                }
            }
        }
    }
}

template<int KH>
__device__ __forceinline__ void sim_and_max(const float* __restrict__ snb,
                                            float (&v)[25], float& m) {
    constexpr int NK = KH ? 25 : 24;
    const float nc = snb[3 * HW2 + 3];
#pragma unroll
    for (int l = 0; l < NK; ++l) {
        const int k = KH ? (24 + l) : l;
        const int off = (k / 7) * HW2 + (k % 7);
        const float nn = snb[off];
        const float sv = __fdividef(v[l], nc * nn + EPS);
        v[l] = sv;
        m = fmaxf(m, sv);
    }
}

template<int KH>
__device__ __forceinline__ void exp_and_sum(float (&v)[25], float m, float& sum) {
    constexpr int NK = KH ? 25 : 24;
#pragma unroll
    for (int l = 0; l < NK; ++l) {
        const float e = __expf(v[l] - m);
        v[l] = e;
        sum += e;
    }
}

template<int KH>
__device__ __forceinline__ void store_q(float* __restrict__ op,
                                        const float (&v)[25], float inv) {
    constexpr int NK = KH ? 25 : 24;
#pragma unroll
    for (int l = 0; l < NK; ++l)
        op[(size_t)l << 14] = v[l] * inv;
}

#define DISPATCH_KH(stmt)                                 \
    do {                                                  \
        if (kh == 0) { constexpr int Q = 0; stmt; }       \
        else         { constexpr int Q = 1; stmt; }       \
    } while (0)

__global__ __launch_bounds__(256, 2) void rsa_kernel(const float* __restrict__ x,
                                                     float* __restrict__ out) {
    __shared__ float4 sx[2][NP2];       // 24.3 KB: [buf][half*NPOS + pos]
    __shared__ float  sn2[NP2];         // 3.0 KB : per-half sum of squares
    __shared__ float  snf[NPOS];        // 1.5 KB : final norms
    __shared__ float  comb[2][2][TW*TH];// 2.0 KB : [m/s][kh][pixel] combine

    const int tid = threadIdx.x;
    const int w   = tid & 31;
    const int hs  = (tid >> 5) & 1;     // channel-half (in-wave)
    const int pr  = (tid >> 6) & 1;     // pixel-pair (wave-uniform)
    const int kh  = tid >> 7;           // k-half (wave-uniform)
    const int w0  = blockIdx.x * TW;
    const int h0  = blockIdx.y * TH;
    const int b   = blockIdx.z;
    const float* __restrict__ xb = x + (size_t)b * C * PLANE;

    const int r0 = 2 * pr;              // pair's first pixel row in tile

    // thread's window-origin bases (all window offsets become DS immediates)
    const int wbase = hs * NPOS + r0 * HW2 + w;
    const float4* const bp0 = &sx[0][0] + wbase;
    const float4* const bp1 = &sx[1][0] + wbase;

    // ---- staging slot metadata (fixed across passes): slot i = tid + 256*j
    int goff[3], pos[3], hh[3];
    bool act[3], inb[3];
#pragma unroll
    for (int j = 0; j < 3; ++j) {
        int i = tid + j * 256;
        act[j] = (i < NP2);
        int ii = act[j] ? i : 0;
        int h  = (ii >= NPOS) ? 1 : 0;
        int p  = ii - h * NPOS;
        int rr = p / HW2, cc = p - rr * HW2;
        int gh = h0 - 3 + rr, gw = w0 - 3 + cc;
        inb[j]  = (gh >= 0) && (gh < H) && (gw >= 0) && (gw < W);
        goff[j] = gh * W + gw;
        pos[j]  = ii;
        hh[j]   = h;
    }

    float4 pf[3];
    float  np[3] = {0.f, 0.f, 0.f};

    auto load_pass = [&](int t) {
#pragma unroll
        for (int j = 0; j < 3; ++j) {
            float4 v = make_float4(0.f, 0.f, 0.f, 0.f);
            if (act[j] && inb[j]) {
                const float* p = xb + (size_t)(t * 8 + hh[j] * 4) * PLANE + goff[j];
                v.x = p[0];
                v.y = p[PLANE];
                v.z = p[2 * PLANE];
                v.w = p[3 * PLANE];
            }
            pf[j] = v;
        }
    };

    auto write_pass = [&](int buf) {
#pragma unroll
        for (int j = 0; j < 3; ++j) {
            if (act[j]) {
                sx[buf][pos[j]] = pf[j];
                float4 v = pf[j];
                np[j] += v.x * v.x + v.y * v.y + v.z * v.z + v.w * v.w;
            }
        }
    };

    float a0[25], a1[25];
#pragma unroll
    for (int l = 0; l < 25; ++l) { a0[l] = 0.f; a1[l] = 0.f; }

    // ---- software-pipelined main loop: prefetch t+1 while computing t
    load_pass(0);
    write_pass(0);
    __syncthreads();
#pragma unroll 2
    for (int t = 0; t < 8; ++t) {
        const float4* bp = (t & 1) ? bp1 : bp0;
        if (t < 7) load_pass(t + 1);
        DISPATCH_KH(compute_q<Q>(bp, a0, a1));
        if (t < 7) write_pass((t & 1) ^ 1);
        __syncthreads();
    }

    // ---- norms: slot owners hold per-half sums over all 8 passes
#pragma unroll
    for (int j = 0; j < 3; ++j)
        if (act[j]) sn2[pos[j]] = np[j];
    __syncthreads();
    for (int i = tid; i < NPOS; i += 256) snf[i] = sqrtf(sn2[i] + sn2[i + NPOS]);
    __syncthreads();

    // ---- cross-channel-half reduce; lane hs keeps pixel row r0+hs
    float v[25];
#pragma unroll
    for (int l = 0; l < 25; ++l) {
        const float t0 = a0[l] + __shfl_xor(a0[l], 32, 64);
        const float t1 = a1[l] + __shfl_xor(a1[l], 32, 64);
        v[l] = hs ? t1 : t0;
    }

    const int prow = r0 + hs;                       // this lane's pixel row
    const float* snb = &snf[0] + prow * HW2 + w;

    float m = -1e30f;
    DISPATCH_KH(sim_and_max<Q>(snb, v, m));

    const int pxi = prow * TW + w;
    comb[0][kh][pxi] = m;
    __syncthreads();
    m = fmaxf(comb[0][0][pxi], comb[0][1][pxi]);

    float sum = 0.f;
    DISPATCH_KH(exp_and_sum<Q>(v, m, sum));
    comb[1][kh][pxi] = sum;
    __syncthreads();
    sum = comb[1][0][pxi] + comb[1][1][pxi];
    const float inv = __fdividef(1.f, sum);

    float* op = out + (((size_t)b * KK + kh * 24) << 14) + ((h0 + prow) << 7) + (w0 + w);
    DISPATCH_KH(store_q<Q>(op, v, inv));
}

extern "C" void kernel_launch(void* const* d_in, const int* in_sizes, int n_in,
                              void* d_out, int out_size, void* d_ws, size_t ws_size,
                              hipStream_t stream) {
    const float* x = (const float*)d_in[0];
    float* out = (float*)d_out;

    dim3 block(256, 1, 1);
    dim3 grid(W / TW, H / TH, NB);  // 4 x 32 x 4 = 512 blocks (2 per CU)
    rsa_kernel<<<grid, block, 0, stream>>>(x, out);
}